// Round 2
// baseline (421.822 us; speedup 1.0000x reference)
//
#include <hip/hip_runtime.h>

#define FNUM 40
#define DIM  64
#define NPAIR 780           // 40*39/2
#define BLOCK 256
#define IN4   (FNUM * DIM / 4)    // 640 float4 per batch row
#define OUT4  (NPAIR * DIM / 4)   // 12480 float4 per batch row

typedef float f32x4 __attribute__((ext_vector_type(4)));

__global__ __launch_bounds__(BLOCK)
void bilinear_fused(const float* __restrict__ in,
                    const float* __restrict__ w,
                    float* __restrict__ out)
{
    __shared__ float sIn[FNUM * DIM];   // 10 KB
    __shared__ float sXW[FNUM * DIM];   // 10 KB
    __shared__ unsigned char sPi[NPAIR];
    __shared__ unsigned char sPj[NPAIR];

    const int tid  = threadIdx.x;
    const int b    = blockIdx.x;
    const int lane = tid & 63;
    const int wv   = tid >> 6;

    // ---- stage inputs[b] into LDS (coalesced float4) ----
    const f32x4* in4 = (const f32x4*)in + (size_t)b * IN4;
    f32x4* sIn4 = (f32x4*)sIn;
    for (int k = tid; k < IN4; k += BLOCK) sIn4[k] = in4[k];

    // ---- pair index table (once per block, trivial) ----
    if (tid < FNUM) {
        int i = tid;
        int off = i * (2 * FNUM - 1 - i) / 2;   // i*(79-i)/2, always integral
        for (int j = i + 1; j < FNUM; ++j) {
            sPi[off] = (unsigned char)i;
            sPj[off] = (unsigned char)j;
            ++off;
        }
    }

    // ---- W column `lane` into registers (coalesced per-d; L1-hot) ----
    float wcol[DIM];
    #pragma unroll
    for (int d = 0; d < DIM; ++d) wcol[d] = w[d * DIM + lane];

    __syncthreads();

    // ---- GEMM: wave wv computes rows wv*10 .. wv*10+9 ----
    // xw[f][lane] = sum_d in[f][d] * W[d][lane]; broadcast in[f][d] via readlane.
    for (int r = 0; r < 10; ++r) {
        int f = wv * 10 + r;
        float rin = sIn[f * DIM + lane];   // lane d holds in[f][d]
        float acc = 0.f;
        #pragma unroll
        for (int d = 0; d < DIM; ++d) {
            float bv = __uint_as_float(
                __builtin_amdgcn_readlane(__float_as_uint(rin), d));
            acc = fmaf(bv, wcol[d], acc);
        }
        sXW[f * DIM + lane] = acc;
    }

    __syncthreads();

    // ---- pair phase: out[b, p*64 + d] = xw[i_p][d] * in[j_p][d] ----
    const f32x4* sXW4 = (const f32x4*)sXW;
    f32x4* out4 = (f32x4*)out + (size_t)b * OUT4;
    for (int idx = tid; idx < OUT4; idx += BLOCK) {
        int p = idx >> 4;          // 16 float4 per pair row
        int q = idx & 15;
        int i = sPi[p];
        int j = sPj[p];
        f32x4 a = sXW4[i * 16 + q];
        f32x4 v = sIn4[j * 16 + q];
        f32x4 o = a * v;
        __builtin_nontemporal_store(o, &out4[idx]);
    }
}

extern "C" void kernel_launch(void* const* d_in, const int* in_sizes, int n_in,
                              void* d_out, int out_size, void* d_ws, size_t ws_size,
                              hipStream_t stream)
{
    const float* in = (const float*)d_in[0];   // [2048, 40, 64] fp32
    const float* w  = (const float*)d_in[1];   // [64, 64] fp32
    float* out = (float*)d_out;                // [2048, 780*64] fp32

    bilinear_fused<<<2048, BLOCK, 0, stream>>>(in, w, out);
}